// Round 1
// 231.704 us; speedup vs baseline: 1.0052x; 1.0052x over previous
//
#include <hip/hip_runtime.h>
#include <stdint.h>

#define B_   128
#define N_   512
#define FIN  128
#define FOUT 64

using bf16x8 = __attribute__((ext_vector_type(8))) short;
using f32x4  = __attribute__((ext_vector_type(4))) float;

// v_cvt_pk_bf16_f32: dst.lo = bf16(lo), dst.hi = bf16(hi), RNE (same as old f2bf)
__device__ inline uint32_t cvt_pk_bf16(float lo, float hi) {
    uint32_t r;
    asm("v_cvt_pk_bf16_f32 %0, %1, %2" : "=v"(r) : "v"(lo), "v"(hi));
    return r;
}
// raw v_exp_f32: D = 2^x (s,t are pre-scaled by log2e in k_h)
__device__ inline float exp2_fast(float x) {
    float r;
    asm("v_exp_f32 %0, %1" : "=v"(r) : "v"(x));
    return r;
}

union bfpack { bf16x8 v; uint32_t w4[4]; };

// ---------------- kernel 1: h = X @ W via bf16 MFMA ----------------
// grid 512 = (b<<2)|quarter, 256 threads (4 waves).
// v2: A-fragments loaded straight from global (the old LDS stage was an
// identity round-trip), W stays in LDS (cross-wave reorg), 16 KB LDS.
// s,t written PRE-SCALED by log2(e) so k_attn can use bare v_exp_f32.
__global__ __launch_bounds__(256, 4) void k_h(const float* __restrict__ X,
                                              const float* __restrict__ W,
                                              const float* __restrict__ a,
                                              uint16_t* __restrict__ htT,
                                              float* __restrict__ s,
                                              float* __restrict__ t) {
    __shared__ bf16x8 wl[16 * 64];   // W fragments: 4 ks x 4 nt, 16 KB

    const int b  = blockIdx.x >> 2;
    const int j0 = (blockIdx.x & 3) * 128;
    const int tid = threadIdx.x;
    const int w = tid >> 6, lane = tid & 63;
    const int q = lane >> 4, m = lane & 15;

    // ---- stage W fragments (ks = w): B[k][n], k=q*8+u, n=m ----
#pragma unroll
    for (int nt = 0; nt < 4; ++nt) {
        float wv[8];
#pragma unroll
        for (int u = 0; u < 8; ++u)
            wv[u] = W[(w * 32 + q * 8 + u) * FOUT + nt * 16 + m];
        bfpack fr;
        fr.w4[0] = cvt_pk_bf16(wv[0], wv[1]);
        fr.w4[1] = cvt_pk_bf16(wv[2], wv[3]);
        fr.w4[2] = cvt_pk_bf16(wv[4], wv[5]);
        fr.w4[3] = cvt_pk_bf16(wv[6], wv[7]);
        wl[(w * 4 + nt) * 64 + lane] = fr.v;
    }
    __syncthreads();

    const float LOG2E = 1.44269504088896340736f;
    float asv[4], adv[4];
#pragma unroll
    for (int nt = 0; nt < 4; ++nt) {
        asv[nt] = a[nt * 16 + m] * LOG2E;          // pre-scale: exp(x)=2^(x*log2e)
        adv[nt] = a[FOUT + nt * 16 + m] * LOG2E;   // (lrelu commutes with pos scale)
    }

    const float* xb = X + ((size_t)(b * N_) + j0) * FIN;

#pragma unroll
    for (int rl = 0; rl < 2; ++rl) {
        const int rt = w + rl * 4;
        f32x4 acc[4] = {{0.f,0.f,0.f,0.f},{0.f,0.f,0.f,0.f},
                        {0.f,0.f,0.f,0.f},{0.f,0.f,0.f,0.f}};
#pragma unroll
        for (int ks = 0; ks < 4; ++ks) {
            const float* src = xb + (size_t)(rt * 16 + m) * FIN + ks * 32 + q * 8;
            float4 v0 = *(const float4*)src;
            float4 v1 = *(const float4*)(src + 4);
            bfpack af;
            af.w4[0] = cvt_pk_bf16(v0.x, v0.y);
            af.w4[1] = cvt_pk_bf16(v0.z, v0.w);
            af.w4[2] = cvt_pk_bf16(v1.x, v1.y);
            af.w4[3] = cvt_pk_bf16(v1.z, v1.w);
#pragma unroll
            for (int nt = 0; nt < 4; ++nt)
                acc[nt] = __builtin_amdgcn_mfma_f32_16x16x32_bf16(
                    af.v, wl[(ks * 4 + nt) * 64 + lane], acc[nt], 0, 0, 0);
        }

        // ---- s,t: per C-row dot with a_src/a_dst, reduce over m lanes ----
        float ps[4], pt[4];
#pragma unroll
        for (int r = 0; r < 4; ++r) {
            float vs = 0.f, vt = 0.f;
#pragma unroll
            for (int nt = 0; nt < 4; ++nt) {
                vs += acc[nt][r] * asv[nt];
                vt += acc[nt][r] * adv[nt];
            }
            vs += __shfl_xor(vs, 1, 64); vs += __shfl_xor(vs, 2, 64);
            vs += __shfl_xor(vs, 4, 64); vs += __shfl_xor(vs, 8, 64);
            vt += __shfl_xor(vt, 1, 64); vt += __shfl_xor(vt, 2, 64);
            vt += __shfl_xor(vt, 4, 64); vt += __shfl_xor(vt, 8, 64);
            ps[r] = vs; pt[r] = vt;
        }
        if (m < 4) {
            float vs = (m == 0) ? ps[0] : (m == 1) ? ps[1] : (m == 2) ? ps[2] : ps[3];
            float vt = (m == 0) ? pt[0] : (m == 1) ? pt[1] : (m == 2) ? pt[2] : pt[3];
            int row = j0 + rt * 16 + q * 4 + m;
            s[b * N_ + row] = vs;
            t[b * N_ + row] = vt;
        }

        // ---- store htT[b][f][j] bf16: C row=q*4+reg -> j, col=m -> f ----
#pragma unroll
        for (int nt = 0; nt < 4; ++nt) {
            uint2 dd;
            dd.x = cvt_pk_bf16(acc[nt][0], acc[nt][1]);
            dd.y = cvt_pk_bf16(acc[nt][2], acc[nt][3]);
            *(uint2*)(htT + (size_t)(b * FOUT + nt * 16 + m) * N_ + j0 + rt * 16 + q * 4) = dd;
        }
    }
}

// ---------------- kernel 2: attention + aggregation (bf16 MFMA) ----------------
// v2: no hstage LDS (htT[b] = 64 KB is L2-resident; read B-frags direct),
// LDS = 2 KB tsh only -> __launch_bounds__(256,4) = 4 blocks/CU for adj latency
// hiding. XCD-bijective swizzle co-locates same-b quads on one XCD's L2.
// Softmax inner loop: bare v_exp_f32 (s,t pre-scaled) + v_cvt_pk_bf16_f32 packing.
__global__ __launch_bounds__(256, 4) void k_attn(const int*    __restrict__ adj,
                                                 const uint16_t* __restrict__ htT,
                                                 const float*  __restrict__ s,
                                                 const float*  __restrict__ t,
                                                 float*        __restrict__ out) {
    __shared__ float tsh[N_];            // 2 KB

    // dispatch d -> XCD d%8; give each XCD a contiguous wg chunk (512%8==0, bijective)
    const int wg = (blockIdx.x & 7) * 64 + (blockIdx.x >> 3);
    const int b  = wg >> 2;
    const int i0 = (wg & 3) * 128;
    const int tid = threadIdx.x;
    const int w = tid >> 6, lane = tid & 63;
    const int q = lane >> 4, m = lane & 15;

    *(float2*)&tsh[tid * 2] = *(const float2*)(t + b * N_ + tid * 2);
    __syncthreads();

    const uint16_t* hb = htT + (size_t)b * FOUT * N_;
    const int ir0 = i0 + w * 16 + m;          // rt0 = w
    const int ir1 = ir0 + 64;                 // rt1 = w + 4
    const float s0 = s[b * N_ + ir0];
    const float s1 = s[b * N_ + ir1];
    const int* ar0 = adj + ((size_t)(b * N_) + ir0) * N_;
    const int* ar1 = adj + ((size_t)(b * N_) + ir1) * N_;

    f32x4 acc0[4] = {{0.f,0.f,0.f,0.f},{0.f,0.f,0.f,0.f},
                     {0.f,0.f,0.f,0.f},{0.f,0.f,0.f,0.f}};
    f32x4 acc1[4] = {{0.f,0.f,0.f,0.f},{0.f,0.f,0.f,0.f},
                     {0.f,0.f,0.f,0.f},{0.f,0.f,0.f,0.f}};
    float ls0 = 0.f, ls1 = 0.f;

    // prefetch ks = 0
    int4 c00 = *(const int4*)(ar0 + q * 8);
    int4 c01 = *(const int4*)(ar0 + q * 8 + 4);
    int4 c10 = *(const int4*)(ar1 + q * 8);
    int4 c11 = *(const int4*)(ar1 + q * 8 + 4);

    for (int ks = 0; ks < 16; ++ks) {
        // issue next-ks adj loads before any compute (clamped, branch-free)
        const int jn = ((ks < 15) ? ks + 1 : ks) * 32 + q * 8;
        int4 n00 = *(const int4*)(ar0 + jn);
        int4 n01 = *(const int4*)(ar0 + jn + 4);
        int4 n10 = *(const int4*)(ar1 + jn);
        int4 n11 = *(const int4*)(ar1 + jn + 4);

        // issue this-ks B-fragment loads early (L1/L2-hot htT[b])
        const uint16_t* hks = hb + ks * 32 + q * 8;
        bf16x8 bf0 = *(const bf16x8*)(hks + (size_t)( 0 + m) * N_);
        bf16x8 bf1 = *(const bf16x8*)(hks + (size_t)(16 + m) * N_);
        bf16x8 bf2 = *(const bf16x8*)(hks + (size_t)(32 + m) * N_);
        bf16x8 bf3 = *(const bf16x8*)(hks + (size_t)(48 + m) * N_);

        const int jb = ks * 32 + q * 8;
        float tj[8];
#pragma unroll
        for (int u = 0; u < 8; ++u) tj[u] = tsh[jb + u];

        int av0[8] = {c00.x, c00.y, c00.z, c00.w, c01.x, c01.y, c01.z, c01.w};
        int av1[8] = {c10.x, c10.y, c10.z, c10.w, c11.x, c11.y, c11.z, c11.w};

        bfpack pk0, pk1;
#pragma unroll
        for (int up = 0; up < 4; ++up) {
            float e; float x;
            e = s0 + tj[2 * up];     e = fmaxf(e, 0.2f * e); x = exp2_fast(e);
            float pa0 = (av0[2 * up] > 0) ? x : 0.0f;
            e = s0 + tj[2 * up + 1]; e = fmaxf(e, 0.2f * e); x = exp2_fast(e);
            float pb0 = (av0[2 * up + 1] > 0) ? x : 0.0f;
            ls0 += pa0 + pb0;
            pk0.w4[up] = cvt_pk_bf16(pa0, pb0);

            e = s1 + tj[2 * up];     e = fmaxf(e, 0.2f * e); x = exp2_fast(e);
            float pa1 = (av1[2 * up] > 0) ? x : 0.0f;
            e = s1 + tj[2 * up + 1]; e = fmaxf(e, 0.2f * e); x = exp2_fast(e);
            float pb1 = (av1[2 * up + 1] > 0) ? x : 0.0f;
            ls1 += pa1 + pb1;
            pk1.w4[up] = cvt_pk_bf16(pa1, pb1);
        }

        acc0[0] = __builtin_amdgcn_mfma_f32_16x16x32_bf16(pk0.v, bf0, acc0[0], 0, 0, 0);
        acc0[1] = __builtin_amdgcn_mfma_f32_16x16x32_bf16(pk0.v, bf1, acc0[1], 0, 0, 0);
        acc0[2] = __builtin_amdgcn_mfma_f32_16x16x32_bf16(pk0.v, bf2, acc0[2], 0, 0, 0);
        acc0[3] = __builtin_amdgcn_mfma_f32_16x16x32_bf16(pk0.v, bf3, acc0[3], 0, 0, 0);
        acc1[0] = __builtin_amdgcn_mfma_f32_16x16x32_bf16(pk1.v, bf0, acc1[0], 0, 0, 0);
        acc1[1] = __builtin_amdgcn_mfma_f32_16x16x32_bf16(pk1.v, bf1, acc1[1], 0, 0, 0);
        acc1[2] = __builtin_amdgcn_mfma_f32_16x16x32_bf16(pk1.v, bf2, acc1[2], 0, 0, 0);
        acc1[3] = __builtin_amdgcn_mfma_f32_16x16x32_bf16(pk1.v, bf3, acc1[3], 0, 0, 0);

        c00 = n00; c01 = n01; c10 = n10; c11 = n11;
    }

    // row-sum l over q groups (lanes differ in bits 4,5)
    ls0 += __shfl_xor(ls0, 16, 64);
    ls0 += __shfl_xor(ls0, 32, 64);
    ls1 += __shfl_xor(ls1, 16, 64);
    ls1 += __shfl_xor(ls1, 32, 64);

#pragma unroll
    for (int reg = 0; reg < 4; ++reg) {
        float lr0 = __shfl(ls0, q * 4 + reg, 64);
        float lr1 = __shfl(ls1, q * 4 + reg, 64);
        float inv0 = 1.0f / lr0, inv1 = 1.0f / lr1;
        int orow0 = i0 + w * 16 + q * 4 + reg;
        size_t ob0 = ((size_t)(b * N_) + orow0) * FOUT + m;
        size_t ob1 = ob0 + (size_t)64 * FOUT;
#pragma unroll
        for (int nt = 0; nt < 4; ++nt) {
            float v0 = acc0[nt][reg] * inv0; v0 = fmaxf(v0, 0.01f * v0);
            float v1 = acc1[nt][reg] * inv1; v1 = fmaxf(v1, 0.01f * v1);
            out[ob0 + nt * 16] = v0;
            out[ob1 + nt * 16] = v1;
        }
    }
}

extern "C" void kernel_launch(void* const* d_in, const int* in_sizes, int n_in,
                              void* d_out, int out_size, void* d_ws, size_t ws_size,
                              hipStream_t stream) {
    const float* X   = (const float*)d_in[0];   // (B, N, FIN) fp32
    const int*   adj = (const int*)  d_in[1];   // (B, N, N) int32
    const float* W   = (const float*)d_in[2];   // (FIN, FOUT) fp32
    const float* a   = (const float*)d_in[3];   // (2*FOUT, 1) fp32
    float* out = (float*)d_out;                 // (B, N, FOUT) fp32

    uint16_t* htT = (uint16_t*)d_ws;                       // B*FOUT*N bf16 = 8 MB
    float* s = (float*)(htT + (size_t)B_ * FOUT * N_);     // 65536 floats
    float* t = s + B_ * N_;                                // 65536 floats

    k_h<<<B_ * 4, 256, 0, stream>>>(X, W, a, htT, s, t);
    k_attn<<<B_ * 4, 256, 0, stream>>>(adj, htT, s, t, out);
}